// Round 5
// baseline (481.803 us; speedup 1.0000x reference)
//
#include <hip/hip_runtime.h>
#include <stdint.h>

// B=4, N=M=4096, C=256
#define CAP 192   // max matches kept per row (lambda~10, Poisson tail => never hit)

typedef __attribute__((ext_vector_type(4))) float f32x4;
typedef __attribute__((ext_vector_type(8))) short bf16x8;

__device__ __forceinline__ float bf2f(ushort u) {
  return __uint_as_float(((unsigned)u) << 16);
}
__device__ __forceinline__ ushort f2bf(float f) {
  unsigned u = __float_as_uint(f);
  return (ushort)((u + 0x7fffu + ((u >> 16) & 1u)) >> 16);  // RNE
}
__device__ __forceinline__ float wredsum(float v) {
#pragma unroll
  for (int o = 32; o; o >>= 1) v += __shfl_xor(v, o);
  return v;
}

// ---------------- GEMM body: Y[r,o] = sum_c A[r,c]*W[o,c] + bias[o] ----------------
// A: [16384,256] bf16 (A_BF16) or f32 (converted during staging)
// W: [256,256] f32 row-major [out,in], converted to bf16 during staging
template <bool A_BF16, typename OutT>
__device__ __forceinline__ void gemm_body(const void* __restrict__ Av,
                                          const float* __restrict__ Wf,
                                          const float* __restrict__ bias,
                                          OutT* __restrict__ Y, int blk,
                                          ushort* As, ushort* Bs) {
  int tid = threadIdx.x;
  int lane = tid & 63, wid = tid >> 6;
  int bm = blk >> 1, bn = blk & 1;
  int r0 = bm * 128, c0 = bn * 128;
  int wr = wid >> 1, wc = wid & 1;
  f32x4 acc[4][4] = {};
  for (int k0 = 0; k0 < 256; k0 += 32) {
    __syncthreads();
#pragma unroll
    for (int p = 0; p < 2; ++p) {
      int u = p * 2048 + tid * 8;
      int row = u >> 5, col = u & 31;
      if constexpr (A_BF16) {
        *(bf16x8*)&As[u] =
            *(const bf16x8*)((const ushort*)Av + (size_t)(r0 + row) * 256 + k0 + col);
      } else {
        const float* Af = (const float*)Av;
        float4 lo = *(const float4*)(Af + (size_t)(r0 + row) * 256 + k0 + col);
        float4 hi = *(const float4*)(Af + (size_t)(r0 + row) * 256 + k0 + col + 4);
        ushort4 o0 = { f2bf(lo.x), f2bf(lo.y), f2bf(lo.z), f2bf(lo.w) };
        ushort4 o1 = { f2bf(hi.x), f2bf(hi.y), f2bf(hi.z), f2bf(hi.w) };
        *(ushort4*)&As[u] = o0;
        *(ushort4*)&As[u + 4] = o1;
      }
      {
        float4 lo = *(const float4*)(Wf + (size_t)(c0 + row) * 256 + k0 + col);
        float4 hi = *(const float4*)(Wf + (size_t)(c0 + row) * 256 + k0 + col + 4);
        ushort4 o0 = { f2bf(lo.x), f2bf(lo.y), f2bf(lo.z), f2bf(lo.w) };
        ushort4 o1 = { f2bf(hi.x), f2bf(hi.y), f2bf(hi.z), f2bf(hi.w) };
        *(ushort4*)&Bs[u] = o0;
        *(ushort4*)&Bs[u + 4] = o1;
      }
    }
    __syncthreads();
    bf16x8 af[4], bfr[4];
    int rsel = lane & 15, ksel = (lane >> 4) * 8;
#pragma unroll
    for (int m = 0; m < 4; ++m)
      af[m] = *(bf16x8*)&As[(wr * 64 + m * 16 + rsel) * 32 + ksel];
#pragma unroll
    for (int n = 0; n < 4; ++n)
      bfr[n] = *(bf16x8*)&Bs[(wc * 64 + n * 16 + rsel) * 32 + ksel];
#pragma unroll
    for (int m = 0; m < 4; ++m)
#pragma unroll
      for (int n = 0; n < 4; ++n)
        acc[m][n] = __builtin_amdgcn_mfma_f32_16x16x32_bf16(af[m], bfr[n], acc[m][n], 0, 0, 0);
  }
  int rbase = r0 + wr * 64 + ((lane >> 4) * 4);
  int cbase = c0 + wc * 64 + (lane & 15);
#pragma unroll
  for (int n = 0; n < 4; ++n) {
    float bv = bias[cbase + n * 16];
#pragma unroll
    for (int m = 0; m < 4; ++m) {
#pragma unroll
      for (int j = 0; j < 4; ++j) {
        float v = acc[m][n][j] + bv;
        size_t idx = (size_t)(rbase + m * 16 + j) * 256 + (cbase + n * 16);
        if constexpr (sizeof(OutT) == 2) Y[idx] = (OutT)f2bf(v);
        else Y[idx] = (OutT)v;
      }
    }
  }
}

// fused Q/K/V projection from f32 inputs: 768 blocks (3 GEMMs x 256)
__global__ __launch_bounds__(256, 2) void gemm3(
    const float* __restrict__ nodesL, const float* __restrict__ nodesR,
    const float* __restrict__ Wq, const float* __restrict__ Wk,
    const float* __restrict__ Wv, const float* __restrict__ bq,
    const float* __restrict__ bk, const float* __restrict__ bv,
    ushort* __restrict__ Qb, ushort* __restrict__ Kb, ushort* __restrict__ Vb) {
  __shared__ __align__(16) ushort As[128 * 32];
  __shared__ __align__(16) ushort Bs[128 * 32];
  int which = blockIdx.x >> 8;
  int blk = blockIdx.x & 255;
  const float* A = (which == 0) ? nodesL : nodesR;
  const float* W = (which == 0) ? Wq : (which == 1) ? Wk : Wv;
  const float* bias = (which == 0) ? bq : (which == 1) ? bk : bv;
  ushort* Y = (which == 0) ? Qb : (which == 1) ? Kb : Vb;
  gemm_body<false, ushort>(A, W, bias, Y, blk, As, Bs);
}

__global__ __launch_bounds__(256, 2) void gemm_out(const ushort* __restrict__ A,
                                                   const float* __restrict__ Wm,
                                                   const float* __restrict__ bias,
                                                   float* __restrict__ Y) {
  __shared__ __align__(16) ushort As[128 * 32];
  __shared__ __align__(16) ushort Bs[128 * 32];
  gemm_body<true, float>(A, Wm, bias, Y, blockIdx.x, As, Bs);
}

// ---------------- column sums of nodes_R (f32) + u-sums of kpts_R ----------------
__global__ __launch_bounds__(256) void sum_nodes(const float* __restrict__ nodesR,
                                                 const float* __restrict__ kptsR,
                                                 float* __restrict__ S,
                                                 float* __restrict__ sumU) {
  int b = blockIdx.x >> 4, ch = blockIdx.x & 15;
  int t = threadIdx.x;
  int c4 = (t & 63) * 4;
  int r0 = b * 4096 + ch * 256 + (t >> 6);
  float4 acc = {0.f, 0.f, 0.f, 0.f};
  for (int k = 0; k < 64; ++k) {
    float4 v = *(const float4*)(nodesR + (size_t)(r0 + k * 4) * 256 + c4);
    acc.x += v.x; acc.y += v.y; acc.z += v.z; acc.w += v.w;
  }
  __shared__ float4 red[256];
  red[t] = acc;
  float u = kptsR[(size_t)(b * 4096 + ch * 256 + t) * 2];
  u = wredsum(u);
  __shared__ float ured[4];
  if ((t & 63) == 0) ured[t >> 6] = u;
  __syncthreads();
  if (t < 64) {
    float4 x = red[t], y = red[t + 64], z = red[t + 128], w = red[t + 192];
    atomicAdd(&S[b * 256 + c4 + 0], x.x + y.x + z.x + w.x);
    atomicAdd(&S[b * 256 + c4 + 1], x.y + y.y + z.y + w.y);
    atomicAdd(&S[b * 256 + c4 + 2], x.z + y.z + z.z + w.z);
    atomicAdd(&S[b * 256 + c4 + 3], x.w + y.w + z.w + w.w);
  }
  if (t == 0) atomicAdd(&sumU[b], ured[0] + ured[1] + ured[2] + ured[3]);
}

// meanV[b][c] = (S[b] . Wv[c,:]) / 4096 + bv[c];  meanU[b] = sumU[b]/4096
__global__ __launch_bounds__(256) void proj_mean(const float* __restrict__ S,
                                                 const float* __restrict__ sumU,
                                                 const float* __restrict__ Wv,
                                                 const float* __restrict__ bv,
                                                 ushort* __restrict__ meanVb,
                                                 float* __restrict__ meanU) {
  int b = blockIdx.x, c = threadIdx.x;
  const float* s = S + b * 256;
  float acc = 0.f;
  for (int k = 0; k < 256; k += 4) {
    float4 w = *(const float4*)(Wv + (size_t)c * 256 + k);
    acc += s[k] * w.x + s[k + 1] * w.y + s[k + 2] * w.z + s[k + 3] * w.w;
  }
  float mv = acc * (1.f / 4096.f) + bv[c];
  meanVb[b * 256 + c] = f2bf(mv);
  if (c == 0) meanU[b] = sumU[b] * (1.f / 4096.f);
}

// ---------------- wave-per-row sparse attention ----------------
__global__ __launch_bounds__(512, 2) void attn_rows(
    const float* __restrict__ kptsL, const float* __restrict__ kptsR,
    const ushort* __restrict__ Qb, const ushort* __restrict__ Kb,
    const ushort* __restrict__ Vb, const float* __restrict__ meanU,
    const ushort* __restrict__ meanVb, float* __restrict__ disp_out,
    float* __restrict__ conf_out, ushort* __restrict__ matched,
    int* __restrict__ rowcnt, int2* __restrict__ rowlist) {
  __shared__ float2 kR[4096];
  __shared__ int bufM[8][CAP];
  __shared__ float bufD[8][CAP];
  __shared__ float bufS[8][CAP];
  int tid = threadIdx.x, lane = tid & 63, wid = tid >> 6;
  int b = blockIdx.x >> 9;
  int n = ((blockIdx.x & 511) << 3) + wid;
  int row = (b << 12) + n;
  int bb = b << 12;
  const float2* kRsrc = (const float2*)kptsR + (size_t)bb;
  for (int i = tid; i < 4096; i += 512) kR[i] = kRsrc[i];
  __syncthreads();
  float2 kL = ((const float2*)kptsL)[(size_t)row];
  ushort4 qv = *(const ushort4*)(Qb + (size_t)row * 256 + lane * 4);
  float q0 = bf2f(qv.x), q1 = bf2f(qv.y), q2 = bf2f(qv.z), q3 = bf2f(qv.w);

  // ---- mask scan: branchless popcount-prefix hit compaction ----
  unsigned long long lmask = (1ull << lane) - 1ull;
  int cnt = 0;
#pragma unroll 4
  for (int m0 = 0; m0 < 4096; m0 += 64) {
    float2 kr = kR[m0 + lane];
    float dv = fabsf(kL.y - kr.y);
    float du = kL.x - kr.x;
    bool hit = (dv < 3.0f) && (du > 0.0f) && (du < 192.0f);
    unsigned long long bal = __ballot(hit);
    int pos = cnt + (int)__popcll(bal & lmask);
    if (hit && pos < CAP) { bufM[wid][pos] = m0 + lane; bufD[wid][pos] = du; }
    cnt += (int)__popcll(bal);
  }
  if (cnt > CAP) cnt = CAP;

  float conf, disp;
  if (cnt == 0) {
    conf = 0.f;
    disp = kL.x - meanU[b];
    if (lane == 0) rowcnt[row] = 0;
    ushort4 st = *(const ushort4*)(meanVb + b * 256 + lane * 4);
    *(ushort4*)(matched + (size_t)row * 256 + lane * 4) = st;
  } else {
    // ---- QK^T for hits (2-way unrolled wave-cooperative dots) ----
    float mx = -1e30f;
    int i = 0;
    for (; i + 1 < cnt; i += 2) {
      int ma = bufM[wid][i], mb = bufM[wid][i + 1];
      ushort4 ka = *(const ushort4*)(Kb + ((size_t)(bb + ma)) * 256 + lane * 4);
      ushort4 kb2 = *(const ushort4*)(Kb + ((size_t)(bb + mb)) * 256 + lane * 4);
      float pa = q0 * bf2f(ka.x) + q1 * bf2f(ka.y) + q2 * bf2f(ka.z) + q3 * bf2f(ka.w);
      float pb = q0 * bf2f(kb2.x) + q1 * bf2f(kb2.y) + q2 * bf2f(kb2.z) + q3 * bf2f(kb2.w);
#pragma unroll
      for (int o = 32; o; o >>= 1) {
        pa += __shfl_xor(pa, o);
        pb += __shfl_xor(pb, o);
      }
      float sa = pa * 0.0625f, sb = pb * 0.0625f;
      if (lane == 0) { bufS[wid][i] = sa; bufS[wid][i + 1] = sb; }
      mx = fmaxf(mx, fmaxf(sa, sb));
    }
    if (i < cnt) {
      int ma = bufM[wid][i];
      ushort4 ka = *(const ushort4*)(Kb + ((size_t)(bb + ma)) * 256 + lane * 4);
      float pa = q0 * bf2f(ka.x) + q1 * bf2f(ka.y) + q2 * bf2f(ka.z) + q3 * bf2f(ka.w);
      pa = wredsum(pa);
      float sa = pa * 0.0625f;
      if (lane == 0) bufS[wid][i] = sa;
      mx = fmaxf(mx, sa);
    }
    // ---- softmax ----
    float psum = 0.f, pdisp = 0.f;
    for (int k = lane; k < cnt; k += 64) {
      float e = expf(bufS[wid][k] - mx);
      bufS[wid][k] = e;
      psum += e;
      pdisp += e * bufD[wid][k];
    }
    psum = wredsum(psum);
    pdisp = wredsum(pdisp);
    float inv = 1.f / psum;
    disp = pdisp * inv;
    conf = 1.f;
    for (int k = lane; k < cnt; k += 64) {
      int2 e;
      e.x = bufM[wid][k];
      e.y = __float_as_int(bufS[wid][k] * inv);
      rowlist[(size_t)row * CAP + k] = e;
    }
    if (lane == 0) rowcnt[row] = cnt;
    // ---- PV (2-way unrolled) ----
    float a0 = 0.f, a1 = 0.f, a2 = 0.f, a3 = 0.f;
    i = 0;
    for (; i + 1 < cnt; i += 2) {
      float wa = bufS[wid][i] * inv, wb = bufS[wid][i + 1] * inv;
      int ma = bufM[wid][i], mb = bufM[wid][i + 1];
      ushort4 va = *(const ushort4*)(Vb + ((size_t)(bb + ma)) * 256 + lane * 4);
      ushort4 vb2 = *(const ushort4*)(Vb + ((size_t)(bb + mb)) * 256 + lane * 4);
      a0 += wa * bf2f(va.x) + wb * bf2f(vb2.x);
      a1 += wa * bf2f(va.y) + wb * bf2f(vb2.y);
      a2 += wa * bf2f(va.z) + wb * bf2f(vb2.z);
      a3 += wa * bf2f(va.w) + wb * bf2f(vb2.w);
    }
    if (i < cnt) {
      float wa = bufS[wid][i] * inv;
      int ma = bufM[wid][i];
      ushort4 va = *(const ushort4*)(Vb + ((size_t)(bb + ma)) * 256 + lane * 4);
      a0 += wa * bf2f(va.x); a1 += wa * bf2f(va.y);
      a2 += wa * bf2f(va.z); a3 += wa * bf2f(va.w);
    }
    ushort4 st = { f2bf(a0), f2bf(a1), f2bf(a2), f2bf(a3) };
    *(ushort4*)(matched + (size_t)row * 256 + lane * 4) = st;
  }
  if (lane == 0) { disp_out[row] = disp; conf_out[row] = conf; }
}

// ---------------- attn_weights: pure streaming fill ----------------
__global__ __launch_bounds__(256) void fill_attn(const int* __restrict__ rowcnt,
                                                 float* __restrict__ attn) {
  int r0 = blockIdx.x * 8;
  int tid = threadIdx.x;
#pragma unroll
  for (int r = 0; r < 8; ++r) {
    int row = r0 + r;
    float fill = (rowcnt[row] == 0) ? (1.f / 4096.f) : 0.f;
    f32x4 fv = { fill, fill, fill, fill };
    f32x4* dst = (f32x4*)(attn + (size_t)row * 4096);
#pragma unroll
    for (int j = 0; j < 4; ++j)
      __builtin_nontemporal_store(fv, dst + j * 256 + tid);
  }
}

__global__ __launch_bounds__(256) void scatter_attn(const int* __restrict__ rowcnt,
                                                    const int2* __restrict__ rowlist,
                                                    float* __restrict__ attn) {
  int lane = threadIdx.x & 63;
  for (int row = blockIdx.x * 4 + (threadIdx.x >> 6); row < 16384; row += gridDim.x * 4) {
    int cnt = rowcnt[row];
    for (int i = lane; i < cnt; i += 64) {
      int2 e = rowlist[(size_t)row * CAP + i];
      attn[(size_t)row * 4096 + e.x] = __int_as_float(e.y);
    }
  }
}

extern "C" void kernel_launch(void* const* d_in, const int* in_sizes, int n_in,
                              void* d_out, int out_size, void* d_ws, size_t ws_size,
                              hipStream_t stream) {
  const float* nodes_L = (const float*)d_in[0];
  const float* nodes_R = (const float*)d_in[1];
  const float* kpts_L = (const float*)d_in[2];
  const float* kpts_R = (const float*)d_in[3];
  const float* Wq = (const float*)d_in[4];
  const float* bq = (const float*)d_in[5];
  const float* Wk = (const float*)d_in[6];
  const float* bk = (const float*)d_in[7];
  const float* Wv = (const float*)d_in[8];
  const float* bv = (const float*)d_in[9];
  const float* Wm = (const float*)d_in[10];
  const float* bm = (const float*)d_in[11];

  float* out = (float*)d_out;            // [4,4096,256]
  float* disp = out + 4194304;           // [4,4096,1]
  float* conf = disp + 16384;            // [4,4096,1]
  float* attn = conf + 16384;            // [4,4096,4096]

  char* ws = (char*)d_ws;
  ushort* Qb = (ushort*)(ws + 0);                 // 8 MB
  ushort* Kb = (ushort*)(ws + 8388608);           // 8 MB
  ushort* Vb = (ushort*)(ws + 16777216);          // 8 MB
  ushort* matched = (ushort*)(ws + 25165824);     // 8 MB
  float* S = (float*)(ws + 33554432);             // 1024 f32 column sums
  float* sumU = (float*)(ws + 33558528);          // 4 f32
  float* meanU = (float*)(ws + 33558592);         // 4 f32
  ushort* meanVb = (ushort*)(ws + 33558656);      // 1024 bf16
  int* rowcnt = (int*)(ws + 33562624);            // 64 KB
  int2* rowlist = (int2*)(ws + 33628160);         // 24 MB

  (void)hipMemsetAsync(S, 0, 4096 + 64, stream);  // zero S + sumU
  sum_nodes<<<64, 256, 0, stream>>>(nodes_R, kpts_R, S, sumU);
  gemm3<<<768, 256, 0, stream>>>(nodes_L, nodes_R, Wq, Wk, Wv, bq, bk, bv, Qb, Kb, Vb);
  proj_mean<<<4, 256, 0, stream>>>(S, sumU, Wv, bv, meanVb, meanU);
  attn_rows<<<2048, 512, 0, stream>>>(kpts_L, kpts_R, Qb, Kb, Vb, meanU, meanVb,
                                      disp, conf, matched, rowcnt, rowlist);
  fill_attn<<<2048, 256, 0, stream>>>(rowcnt, attn);
  scatter_attn<<<512, 256, 0, stream>>>(rowcnt, rowlist, attn);
  gemm_out<<<256, 256, 0, stream>>>(matched, Wm, bm, out);
}

// Round 6
// 438.176 us; speedup vs baseline: 1.0996x; 1.0996x over previous
//
#include <hip/hip_runtime.h>
#include <stdint.h>

// B=4, N=M=4096, C=256
#define CAP 192   // max matches kept per row (lambda~10, Poisson tail => never hit)

typedef __attribute__((ext_vector_type(4))) float f32x4;
typedef __attribute__((ext_vector_type(8))) short bf16x8;

__device__ __forceinline__ float bf2f(ushort u) {
  return __uint_as_float(((unsigned)u) << 16);
}
__device__ __forceinline__ ushort f2bf(float f) {
  unsigned u = __float_as_uint(f);
  return (ushort)((u + 0x7fffu + ((u >> 16) & 1u)) >> 16);  // RNE
}
__device__ __forceinline__ float wredsum(float v) {
#pragma unroll
  for (int o = 32; o; o >>= 1) v += __shfl_xor(v, o);
  return v;
}

// ---------------- GEMM body: Y[r,o] = sum_c A[r,c]*W[o,c] + bias[o] ----------------
// A: [16384,256] bf16 (A_BF16) or f32 (converted during staging)
// W: [256,256] f32 row-major [out,in], converted to bf16 during staging
template <bool A_BF16, typename OutT>
__device__ __forceinline__ void gemm_body(const void* __restrict__ Av,
                                          const float* __restrict__ Wf,
                                          const float* __restrict__ bias,
                                          OutT* __restrict__ Y, int blk,
                                          ushort* As, ushort* Bs) {
  int tid = threadIdx.x;
  int lane = tid & 63, wid = tid >> 6;
  int bm = blk >> 1, bn = blk & 1;
  int r0 = bm * 128, c0 = bn * 128;
  int wr = wid >> 1, wc = wid & 1;
  f32x4 acc[4][4] = {};
  for (int k0 = 0; k0 < 256; k0 += 32) {
    __syncthreads();
#pragma unroll
    for (int p = 0; p < 2; ++p) {
      int u = p * 2048 + tid * 8;
      int row = u >> 5, col = u & 31;
      if constexpr (A_BF16) {
        *(bf16x8*)&As[u] =
            *(const bf16x8*)((const ushort*)Av + (size_t)(r0 + row) * 256 + k0 + col);
      } else {
        const float* Af = (const float*)Av;
        float4 lo = *(const float4*)(Af + (size_t)(r0 + row) * 256 + k0 + col);
        float4 hi = *(const float4*)(Af + (size_t)(r0 + row) * 256 + k0 + col + 4);
        ushort4 o0 = { f2bf(lo.x), f2bf(lo.y), f2bf(lo.z), f2bf(lo.w) };
        ushort4 o1 = { f2bf(hi.x), f2bf(hi.y), f2bf(hi.z), f2bf(hi.w) };
        *(ushort4*)&As[u] = o0;
        *(ushort4*)&As[u + 4] = o1;
      }
      {
        float4 lo = *(const float4*)(Wf + (size_t)(c0 + row) * 256 + k0 + col);
        float4 hi = *(const float4*)(Wf + (size_t)(c0 + row) * 256 + k0 + col + 4);
        ushort4 o0 = { f2bf(lo.x), f2bf(lo.y), f2bf(lo.z), f2bf(lo.w) };
        ushort4 o1 = { f2bf(hi.x), f2bf(hi.y), f2bf(hi.z), f2bf(hi.w) };
        *(ushort4*)&Bs[u] = o0;
        *(ushort4*)&Bs[u + 4] = o1;
      }
    }
    __syncthreads();
    bf16x8 af[4], bfr[4];
    int rsel = lane & 15, ksel = (lane >> 4) * 8;
#pragma unroll
    for (int m = 0; m < 4; ++m)
      af[m] = *(bf16x8*)&As[(wr * 64 + m * 16 + rsel) * 32 + ksel];
#pragma unroll
    for (int n = 0; n < 4; ++n)
      bfr[n] = *(bf16x8*)&Bs[(wc * 64 + n * 16 + rsel) * 32 + ksel];
#pragma unroll
    for (int m = 0; m < 4; ++m)
#pragma unroll
      for (int n = 0; n < 4; ++n)
        acc[m][n] = __builtin_amdgcn_mfma_f32_16x16x32_bf16(af[m], bfr[n], acc[m][n], 0, 0, 0);
  }
  int rbase = r0 + wr * 64 + ((lane >> 4) * 4);
  int cbase = c0 + wc * 64 + (lane & 15);
#pragma unroll
  for (int n = 0; n < 4; ++n) {
    float bv = bias[cbase + n * 16];
#pragma unroll
    for (int m = 0; m < 4; ++m) {
#pragma unroll
      for (int j = 0; j < 4; ++j) {
        float v = acc[m][n][j] + bv;
        size_t idx = (size_t)(rbase + m * 16 + j) * 256 + (cbase + n * 16);
        if constexpr (sizeof(OutT) == 2) Y[idx] = (OutT)f2bf(v);
        else Y[idx] = (OutT)v;
      }
    }
  }
}

// fused Q/K/V projection from f32 inputs: 768 blocks (3 GEMMs x 256)
__global__ __launch_bounds__(256, 2) void gemm3(
    const float* __restrict__ nodesL, const float* __restrict__ nodesR,
    const float* __restrict__ Wq, const float* __restrict__ Wk,
    const float* __restrict__ Wv, const float* __restrict__ bq,
    const float* __restrict__ bk, const float* __restrict__ bv,
    ushort* __restrict__ Qb, ushort* __restrict__ Kb, ushort* __restrict__ Vb) {
  __shared__ __align__(16) ushort As[128 * 32];
  __shared__ __align__(16) ushort Bs[128 * 32];
  int which = blockIdx.x >> 8;
  int blk = blockIdx.x & 255;
  const float* A = (which == 0) ? nodesL : nodesR;
  const float* W = (which == 0) ? Wq : (which == 1) ? Wk : Wv;
  const float* bias = (which == 0) ? bq : (which == 1) ? bk : bv;
  ushort* Y = (which == 0) ? Qb : (which == 1) ? Kb : Vb;
  gemm_body<false, ushort>(A, W, bias, Y, blk, As, Bs);
}

__global__ __launch_bounds__(256, 2) void gemm_out(const ushort* __restrict__ A,
                                                   const float* __restrict__ Wm,
                                                   const float* __restrict__ bias,
                                                   float* __restrict__ Y) {
  __shared__ __align__(16) ushort As[128 * 32];
  __shared__ __align__(16) ushort Bs[128 * 32];
  gemm_body<true, float>(A, Wm, bias, Y, blockIdx.x, As, Bs);
}

// ---------------- column sums of nodes_R (f32) + u-sums of kpts_R ----------------
// no atomics: each block writes its own partial slot S16[b][ch][256], sumU16[b][ch]
__global__ __launch_bounds__(256) void sum_nodes(const float* __restrict__ nodesR,
                                                 const float* __restrict__ kptsR,
                                                 float* __restrict__ S16,
                                                 float* __restrict__ sumU16) {
  int b = blockIdx.x >> 4, ch = blockIdx.x & 15;
  int t = threadIdx.x;
  int c4 = (t & 63) * 4;
  int r0 = b * 4096 + ch * 256 + (t >> 6);
  float4 acc = {0.f, 0.f, 0.f, 0.f};
  for (int k = 0; k < 64; ++k) {
    float4 v = *(const float4*)(nodesR + (size_t)(r0 + k * 4) * 256 + c4);
    acc.x += v.x; acc.y += v.y; acc.z += v.z; acc.w += v.w;
  }
  __shared__ float4 red[256];
  red[t] = acc;
  float u = kptsR[(size_t)(b * 4096 + ch * 256 + t) * 2];
  u = wredsum(u);
  __shared__ float ured[4];
  if ((t & 63) == 0) ured[t >> 6] = u;
  __syncthreads();
  if (t < 64) {
    float4 x = red[t], y = red[t + 64], z = red[t + 128], w = red[t + 192];
    float4 s = { x.x + y.x + z.x + w.x, x.y + y.y + z.y + w.y,
                 x.z + y.z + z.z + w.z, x.w + y.w + z.w + w.w };
    *(float4*)(S16 + (size_t)(b * 16 + ch) * 256 + t * 4) = s;
  }
  if (t == 0) sumU16[b * 16 + ch] = ured[0] + ured[1] + ured[2] + ured[3];
}

// meanV[b][c] = (sum_ch S16[b][ch] . Wv[c,:]) / 4096 + bv[c];  meanU[b] = sum/4096
__global__ __launch_bounds__(256) void proj_mean(const float* __restrict__ S16,
                                                 const float* __restrict__ sumU16,
                                                 const float* __restrict__ Wv,
                                                 const float* __restrict__ bv,
                                                 ushort* __restrict__ meanVb,
                                                 float* __restrict__ meanU) {
  int b = blockIdx.x, c = threadIdx.x;
  __shared__ float s[256];
  float a0 = 0.f;
  for (int ch = 0; ch < 16; ++ch) a0 += S16[(size_t)(b * 16 + ch) * 256 + c];
  s[c] = a0;
  __syncthreads();
  float acc = 0.f;
  for (int k = 0; k < 256; k += 4) {
    float4 w = *(const float4*)(Wv + (size_t)c * 256 + k);
    acc += s[k] * w.x + s[k + 1] * w.y + s[k + 2] * w.z + s[k + 3] * w.w;
  }
  float mv = acc * (1.f / 4096.f) + bv[c];
  meanVb[b * 256 + c] = f2bf(mv);
  if (c == 0) {
    float su = 0.f;
    for (int ch = 0; ch < 16; ++ch) su += sumU16[b * 16 + ch];
    meanU[b] = su * (1.f / 4096.f);
  }
}

// ---------------- fused: scan + softmax + PV + attn-row write ----------------
__global__ __launch_bounds__(512, 2) void attn_fused(
    const float* __restrict__ kptsL, const float* __restrict__ kptsR,
    const ushort* __restrict__ Qb, const ushort* __restrict__ Kb,
    const ushort* __restrict__ Vb, const float* __restrict__ meanU,
    const ushort* __restrict__ meanVb, float* __restrict__ disp_out,
    float* __restrict__ conf_out, ushort* __restrict__ matched,
    float* __restrict__ attn) {
  __shared__ float2 kR[4096];
  __shared__ int bufM[8][CAP];
  __shared__ float bufD[8][CAP];
  __shared__ float bufS[8][CAP];
  int tid = threadIdx.x, lane = tid & 63, wid = tid >> 6;
  int b = blockIdx.x >> 9;
  int n = ((blockIdx.x & 511) << 3) + wid;
  int row = (b << 12) + n;
  int bb = b << 12;

  // issue the row's zero-stream immediately: 16 KB/wave of nontemporal stores
  // whose latency hides under the LDS staging + mask scan below.
  float* rowp = attn + (size_t)row * 4096;
  {
    f32x4 zv = {0.f, 0.f, 0.f, 0.f};
    f32x4* dst = (f32x4*)rowp;
#pragma unroll
    for (int j = 0; j < 16; ++j)
      __builtin_nontemporal_store(zv, dst + j * 64 + lane);
  }

  const float2* kRsrc = (const float2*)kptsR + (size_t)bb;
  for (int i = tid; i < 4096; i += 512) kR[i] = kRsrc[i];
  __syncthreads();
  float2 kL = ((const float2*)kptsL)[(size_t)row];
  ushort4 qv = *(const ushort4*)(Qb + (size_t)row * 256 + lane * 4);
  float q0 = bf2f(qv.x), q1 = bf2f(qv.y), q2 = bf2f(qv.z), q3 = bf2f(qv.w);

  // ---- mask scan: branchless popcount-prefix hit compaction ----
  unsigned long long lmask = (1ull << lane) - 1ull;
  int cnt = 0;
#pragma unroll 4
  for (int m0 = 0; m0 < 4096; m0 += 64) {
    float2 kr = kR[m0 + lane];
    float dv = fabsf(kL.y - kr.y);
    float du = kL.x - kr.x;
    bool hit = (dv < 3.0f) && (du > 0.0f) && (du < 192.0f);
    unsigned long long bal = __ballot(hit);
    int pos = cnt + (int)__popcll(bal & lmask);
    if (hit && pos < CAP) { bufM[wid][pos] = m0 + lane; bufD[wid][pos] = du; }
    cnt += (int)__popcll(bal);
  }
  if (cnt > CAP) cnt = CAP;

  float conf, disp;
  if (cnt == 0) {
    conf = 0.f;
    disp = kL.x - meanU[b];
    ushort4 st = *(const ushort4*)(meanVb + b * 256 + lane * 4);
    *(ushort4*)(matched + (size_t)row * 256 + lane * 4) = st;
    // overwrite the zero row with the uniform weight (rare: ~e^-10 of rows)
    asm volatile("s_waitcnt vmcnt(0)" ::: "memory");
    const float fill = 1.f / 4096.f;
    f32x4 fv = { fill, fill, fill, fill };
    f32x4* dst = (f32x4*)rowp;
#pragma unroll
    for (int j = 0; j < 16; ++j)
      __builtin_nontemporal_store(fv, dst + j * 64 + lane);
  } else {
    // ---- QK^T for hits (2-way unrolled wave-cooperative dots) ----
    float mx = -1e30f;
    int i = 0;
    for (; i + 1 < cnt; i += 2) {
      int ma = bufM[wid][i], mb = bufM[wid][i + 1];
      ushort4 ka = *(const ushort4*)(Kb + ((size_t)(bb + ma)) * 256 + lane * 4);
      ushort4 kb2 = *(const ushort4*)(Kb + ((size_t)(bb + mb)) * 256 + lane * 4);
      float pa = q0 * bf2f(ka.x) + q1 * bf2f(ka.y) + q2 * bf2f(ka.z) + q3 * bf2f(ka.w);
      float pb = q0 * bf2f(kb2.x) + q1 * bf2f(kb2.y) + q2 * bf2f(kb2.z) + q3 * bf2f(kb2.w);
#pragma unroll
      for (int o = 32; o; o >>= 1) {
        pa += __shfl_xor(pa, o);
        pb += __shfl_xor(pb, o);
      }
      float sa = pa * 0.0625f, sb = pb * 0.0625f;
      if (lane == 0) { bufS[wid][i] = sa; bufS[wid][i + 1] = sb; }
      mx = fmaxf(mx, fmaxf(sa, sb));
    }
    if (i < cnt) {
      int ma = bufM[wid][i];
      ushort4 ka = *(const ushort4*)(Kb + ((size_t)(bb + ma)) * 256 + lane * 4);
      float pa = q0 * bf2f(ka.x) + q1 * bf2f(ka.y) + q2 * bf2f(ka.z) + q3 * bf2f(ka.w);
      pa = wredsum(pa);
      float sa = pa * 0.0625f;
      if (lane == 0) bufS[wid][i] = sa;
      mx = fmaxf(mx, sa);
    }
    // ---- softmax ----
    float psum = 0.f, pdisp = 0.f;
    for (int k = lane; k < cnt; k += 64) {
      float e = expf(bufS[wid][k] - mx);
      bufS[wid][k] = e;
      psum += e;
      pdisp += e * bufD[wid][k];
    }
    psum = wredsum(psum);
    pdisp = wredsum(pdisp);
    float inv = 1.f / psum;
    disp = pdisp * inv;
    conf = 1.f;
    // normalize weights in place (per-wave LDS, wave-coherent)
    for (int k = lane; k < cnt; k += 64) bufS[wid][k] *= inv;
    // ---- PV (2-way unrolled) ----
    float a0 = 0.f, a1 = 0.f, a2 = 0.f, a3 = 0.f;
    i = 0;
    for (; i + 1 < cnt; i += 2) {
      float wa = bufS[wid][i], wb = bufS[wid][i + 1];
      int ma = bufM[wid][i], mb = bufM[wid][i + 1];
      ushort4 va = *(const ushort4*)(Vb + ((size_t)(bb + ma)) * 256 + lane * 4);
      ushort4 vb2 = *(const ushort4*)(Vb + ((size_t)(bb + mb)) * 256 + lane * 4);
      a0 += wa * bf2f(va.x) + wb * bf2f(vb2.x);
      a1 += wa * bf2f(va.y) + wb * bf2f(vb2.y);
      a2 += wa * bf2f(va.z) + wb * bf2f(vb2.z);
      a3 += wa * bf2f(va.w) + wb * bf2f(vb2.w);
    }
    if (i < cnt) {
      float wa = bufS[wid][i];
      int ma = bufM[wid][i];
      ushort4 va = *(const ushort4*)(Vb + ((size_t)(bb + ma)) * 256 + lane * 4);
      a0 += wa * bf2f(va.x); a1 += wa * bf2f(va.y);
      a2 += wa * bf2f(va.z); a3 += wa * bf2f(va.w);
    }
    ushort4 st = { f2bf(a0), f2bf(a1), f2bf(a2), f2bf(a3) };
    *(ushort4*)(matched + (size_t)row * 256 + lane * 4) = st;
    // ---- sparse scatter of normalized weights (after zero-stores retire) ----
    asm volatile("s_waitcnt vmcnt(0)" ::: "memory");
    for (int k = lane; k < cnt; k += 64)
      rowp[bufM[wid][k]] = bufS[wid][k];
  }
  if (lane == 0) { disp_out[row] = disp; conf_out[row] = conf; }
}

extern "C" void kernel_launch(void* const* d_in, const int* in_sizes, int n_in,
                              void* d_out, int out_size, void* d_ws, size_t ws_size,
                              hipStream_t stream) {
  const float* nodes_L = (const float*)d_in[0];
  const float* nodes_R = (const float*)d_in[1];
  const float* kpts_L = (const float*)d_in[2];
  const float* kpts_R = (const float*)d_in[3];
  const float* Wq = (const float*)d_in[4];
  const float* bq = (const float*)d_in[5];
  const float* Wk = (const float*)d_in[6];
  const float* bk = (const float*)d_in[7];
  const float* Wv = (const float*)d_in[8];
  const float* bv = (const float*)d_in[9];
  const float* Wm = (const float*)d_in[10];
  const float* bm = (const float*)d_in[11];

  float* out = (float*)d_out;            // [4,4096,256]
  float* disp = out + 4194304;           // [4,4096,1]
  float* conf = disp + 16384;            // [4,4096,1]
  float* attn = conf + 16384;            // [4,4096,4096]

  char* ws = (char*)d_ws;
  ushort* Qb = (ushort*)(ws + 0);                 // 8 MB
  ushort* Kb = (ushort*)(ws + 8388608);           // 8 MB
  ushort* Vb = (ushort*)(ws + 16777216);          // 8 MB
  ushort* matched = (ushort*)(ws + 25165824);     // 8 MB
  float* S16 = (float*)(ws + 33554432);           // 64 KB partial column sums
  float* sumU16 = (float*)(ws + 33620224);        // 64 f32
  float* meanU = (float*)(ws + 33620480);         // 4 f32
  ushort* meanVb = (ushort*)(ws + 33620544);      // 1024 bf16

  sum_nodes<<<64, 256, 0, stream>>>(nodes_R, kpts_R, S16, sumU16);
  gemm3<<<768, 256, 0, stream>>>(nodes_L, nodes_R, Wq, Wk, Wv, bq, bk, bv, Qb, Kb, Vb);
  proj_mean<<<4, 256, 0, stream>>>(S16, sumU16, Wv, bv, meanVb, meanU);
  attn_fused<<<2048, 512, 0, stream>>>(kpts_L, kpts_R, Qb, Kb, Vb, meanU, meanVb,
                                       disp, conf, matched, attn);
  gemm_out<<<256, 256, 0, stream>>>(matched, Wm, bm, out);
}